// Round 9
// baseline (293.416 us; speedup 1.0000x reference)
//
#include <hip/hip_runtime.h>
#include <hip/hip_bf16.h>

#define B_    8
#define N_    1024
#define C_    512
#define H_    4
#define HD_   128
#define BN_   (B_ * N_)      // 8192
#define QKVC_ 1536
#define SCALE_ 0.08838834764831845f  // 128^-0.5

typedef __bf16 bf16;
typedef __bf16 bf16x8 __attribute__((ext_vector_type(8)));
typedef float  floatx4 __attribute__((ext_vector_type(4)));

__device__ __forceinline__ void gload_lds16(const bf16* g, bf16* l) {
    __builtin_amdgcn_global_load_lds(
        (const __attribute__((address_space(1))) void*)g,
        (__attribute__((address_space(3))) void*)l, 16, 0, 0);
}

// ---------------------------------------------------------------------------
// Kernel 0: fp32 -> bf16 conversion for x, w_qkv, w_proj.
// ---------------------------------------------------------------------------
__global__ __launch_bounds__(256) void cvt_bf16(const float* __restrict__ x,  bf16* __restrict__ xb,
                                                const float* __restrict__ wq, bf16* __restrict__ wqb,
                                                const float* __restrict__ wp, bf16* __restrict__ wpb) {
    int id = blockIdx.x * 256 + threadIdx.x;
    const float* s; bf16* d; int off;
    if (id < 524288)      { s = x;  d = xb;  off = id; }
    else if (id < 622592) { s = wq; d = wqb; off = id - 524288; }
    else                  { s = wp; d = wpb; off = id - 622592; }
    const float4* sp = (const float4*)s + (size_t)off * 2;
    float4 f0 = sp[0], f1 = sp[1];
    bf16x8 v;
    v[0] = (bf16)f0.x; v[1] = (bf16)f0.y; v[2] = (bf16)f0.z; v[3] = (bf16)f0.w;
    v[4] = (bf16)f1.x; v[5] = (bf16)f1.y; v[6] = (bf16)f1.z; v[7] = (bf16)f1.w;
    ((bf16x8*)d)[off] = v;
}

// ---------------------------------------------------------------------------
// m97-class GEMM (proven): C[m][n] = sum_k A[m][k]*Bw[n][k] (+bias)
// ---------------------------------------------------------------------------
template<int TN, int NOUT, bool F32OUT>
__global__ __launch_bounds__(256) void gemm_bt(const bf16* __restrict__ A,
                                               const bf16* __restrict__ Bw,
                                               const float* __restrict__ bias,
                                               void* __restrict__ Cout) {
    constexpr int NT = TN / 32;
    const int t = threadIdx.x;
    const int wave = t >> 6, lane = t & 63;
    const int quad = lane >> 4, l16 = lane & 15;
    const int ro = lane >> 3;
    const int ch = (lane & 7) ^ ro;

    const int m_base = blockIdx.x * 128;
    const int n_base = blockIdx.y * TN;
    const int wave_r = (wave & 1) * 64;
    const int wave_c = (wave >> 1) * (TN / 2);

    __shared__ bf16 As[128 * 64];
    __shared__ bf16 Bs[TN * 64];

    floatx4 acc[4][NT] = {};

    for (int k0 = 0; k0 < 512; k0 += 64) {
        __syncthreads();
#pragma unroll
        for (int j = 0; j < 4; j++) {
            int r0 = (wave * 4 + j) * 8;
            gload_lds16(A + (size_t)(m_base + r0 + ro) * 512 + k0 + ch * 8,
                        As + r0 * 64);
        }
#pragma unroll
        for (int j = 0; j < TN / 32; j++) {
            int r0 = (wave * (TN / 32) + j) * 8;
            gload_lds16(Bw + (size_t)(n_base + r0 + ro) * 512 + k0 + ch * 8,
                        Bs + r0 * 64);
        }
        __syncthreads();

#pragma unroll
        for (int kk = 0; kk < 2; kk++) {
            const int kc = kk * 4 + quad;
            bf16x8 af[4], bfr[NT];
#pragma unroll
            for (int mt = 0; mt < 4; mt++) {
                int r = wave_r + mt * 16 + l16;
                af[mt] = *(const bf16x8*)&As[r * 64 + ((kc ^ (r & 7)) * 8)];
            }
#pragma unroll
            for (int nt = 0; nt < NT; nt++) {
                int r = wave_c + nt * 16 + l16;
                bfr[nt] = *(const bf16x8*)&Bs[r * 64 + ((kc ^ (r & 7)) * 8)];
            }
#pragma unroll
            for (int mt = 0; mt < 4; mt++)
#pragma unroll
                for (int nt = 0; nt < NT; nt++)
                    acc[mt][nt] = __builtin_amdgcn_mfma_f32_16x16x32_bf16(
                        af[mt], bfr[nt], acc[mt][nt], 0, 0, 0);
        }
    }

#pragma unroll
    for (int nt = 0; nt < NT; nt++) {
        int col = n_base + wave_c + nt * 16 + l16;
        float bi = 0.f;
        if constexpr (F32OUT) bi = bias[col];
#pragma unroll
        for (int mt = 0; mt < 4; mt++) {
#pragma unroll
            for (int r = 0; r < 4; r++) {
                int row = m_base + wave_r + mt * 16 + quad * 4 + r;
                if constexpr (F32OUT)
                    ((float*)Cout)[(size_t)row * NOUT + col] = acc[mt][nt][r] + bi;
                else
                    ((bf16*)Cout)[(size_t)row * NOUT + col] = (bf16)acc[mt][nt][r];
            }
        }
    }
}

// ---------------------------------------------------------------------------
// Fused CIM flash attention — shared-score, 2 output heads / block.
// R9: (a) XCD swizzle: linear%16 = (b,split) so the 32 blocks sharing one
//     KV-half land on one XCD (L2-local DMA drains);
//     (b) LDS 53 KB (Pb shared across p; Vt unpadded [256][32], chunk
//     swizzle c^(((r>>1)^(r>>2))&3)) -> 3 blocks/CU.
// ---------------------------------------------------------------------------
__global__ __launch_bounds__(256, 3) void flash_attn(const bf16* __restrict__ qkv,
                                                     const float* __restrict__ w_main,
                                                     const float* __restrict__ w_rest,
                                                     bf16* __restrict__ po,
                                                     float* __restrict__ ml) {
    const int lin = blockIdx.x;          // 0..511
    const int bs = lin & 15;             // same-KV blocks share lin%16 -> same XCD
    const int b = bs >> 1, split = bs & 1;
    const int rest = lin >> 4;           // 0..31
    const int n0 = (rest & 15) * 64;
    const int hg = rest >> 4;            // heads 2hg, 2hg+1

    const int t = threadIdx.x;
    const int wave = t >> 6, lane = t & 63;
    const int quad = lane >> 4, l16 = lane & 15;

    // mix coefficients c[p][j] = M[2hg+p][j] * SCALE
    float c[2][4];
#pragma unroll
    for (int p = 0; p < 2; p++) {
        int i = 2 * hg + p;
#pragma unroll
        for (int j = 0; j < 4; j++) {
            float mij = (j == i) ? w_main[i]
                                 : w_rest[i * (H_ - 1) + (j - (j > i ? 1 : 0))];
            c[p][j] = mij * SCALE_;
        }
    }

    __shared__ bf16 Kt[32 * 512];        // 32 KB, XOR-swizzled
    __shared__ bf16 Vt[256 * 32];        // 16 KB, chunk-swizzled, unpadded
    __shared__ bf16 Pb[4][16][40];       // 5.1 KB, shared across p (total 53 KB)

    // raw Q fragments (A-layout) — mix applied to fp32 scores
    bf16x8 qf[16];
    const int qrow = n0 + wave * 16 + l16;
    const bf16* qbase = qkv + (size_t)(b * N_ + qrow) * QKVC_;
#pragma unroll
    for (int kk = 0; kk < 16; kk++)
        qf[kk] = *(const bf16x8*)(qbase + kk * 32 + quad * 8);

    bf16x8 vones;
#pragma unroll
    for (int j = 0; j < 8; j++) vones[j] = (bf16)1.0f;

    floatx4 o[2][8] = {};
    float mrow[2][4], lrow[2][4];
#pragma unroll
    for (int p = 0; p < 2; p++)
#pragma unroll
        for (int r = 0; r < 4; r++) { mrow[p][r] = -1e30f; lrow[p][r] = 0.f; }

    const bf16* kvbase = qkv + (size_t)(b * N_) * QKVC_;
    const int vg = t & 3, vp = t >> 2;   // V-stage: keys 8vg..+7, dims 4vp..+3
    const int m_begin = split * 512;

    for (int m0 = m_begin; m0 < m_begin + 512; m0 += 32) {
        __syncthreads();
        // K tile via DMA: wave w stages rows 8w..8w+7 (XOR chunk swizzle)
#pragma unroll
        for (int j = 0; j < 8; j++) {
            int r = wave * 8 + j;
            gload_lds16(kvbase + (size_t)(m0 + r) * QKVC_ + 512 + ((lane ^ (r & 7)) << 3),
                        Kt + r * 512);
        }
        // V tile (head-pair, 256 dims): register transpose, 8B loads,
        // swizzled store: chunk vg of dim-row r at vg ^ (((r>>1)^(r>>2))&3)
        {
            const bf16* vs = kvbase + (size_t)(m0 + 8 * vg) * QKVC_ + 1024 + hg * 256 + 4 * vp;
            uint2 dv[8];
#pragma unroll
            for (int j = 0; j < 8; j++)
                dv[j] = *(const uint2*)(vs + (size_t)j * QKVC_);
            uint4 rr[4];
            rr[0].x = (dv[0].x & 0xffffu) | (dv[1].x << 16);
            rr[0].y = (dv[2].x & 0xffffu) | (dv[3].x << 16);
            rr[0].z = (dv[4].x & 0xffffu) | (dv[5].x << 16);
            rr[0].w = (dv[6].x & 0xffffu) | (dv[7].x << 16);
            rr[1].x = (dv[0].x >> 16) | (dv[1].x & 0xffff0000u);
            rr[1].y = (dv[2].x >> 16) | (dv[3].x & 0xffff0000u);
            rr[1].z = (dv[4].x >> 16) | (dv[5].x & 0xffff0000u);
            rr[1].w = (dv[6].x >> 16) | (dv[7].x & 0xffff0000u);
            rr[2].x = (dv[0].y & 0xffffu) | (dv[1].y << 16);
            rr[2].y = (dv[2].y & 0xffffu) | (dv[3].y << 16);
            rr[2].z = (dv[4].y & 0xffffu) | (dv[5].y << 16);
            rr[2].w = (dv[6].y & 0xffffu) | (dv[7].y << 16);
            rr[3].x = (dv[0].y >> 16) | (dv[1].y & 0xffff0000u);
            rr[3].y = (dv[2].y >> 16) | (dv[3].y & 0xffff0000u);
            rr[3].z = (dv[4].y >> 16) | (dv[5].y & 0xffff0000u);
            rr[3].w = (dv[6].y >> 16) | (dv[7].y & 0xffff0000u);
#pragma unroll
            for (int i = 0; i < 4; i++) {
                int r = 4 * vp + i;
                *(uint4*)&Vt[r * 32 + 8 * (vg ^ (((r >> 1) ^ (r >> 2)) & 3))] = rr[i];
            }
        }
        __syncthreads();

        // Per-head scores: s[j] = q_j @ k_j^T  (one pass over 512 cols)
        floatx4 s[4][2] = {};
#pragma unroll
        for (int kk = 0; kk < 16; kk++) {
#pragma unroll
            for (int nt = 0; nt < 2; nt++) {
                int r = nt * 16 + l16;
                bf16x8 kb = *(const bf16x8*)&Kt[r * 512 + (((kk * 4 + quad) ^ (r & 7)) << 3)];
                s[kk >> 2][nt] = __builtin_amdgcn_mfma_f32_16x16x32_bf16(
                    qf[kk], kb, s[kk >> 2][nt], 0, 0, 0);
            }
        }

        // Per output head p: mix -> online softmax -> P staging -> PV
#pragma unroll
        for (int p = 0; p < 2; p++) {
            floatx4 ms0, ms1;
#pragma unroll
            for (int r = 0; r < 4; r++) {
                ms0[r] = c[p][0] * s[0][0][r] + c[p][1] * s[1][0][r]
                       + c[p][2] * s[2][0][r] + c[p][3] * s[3][0][r];
                ms1[r] = c[p][0] * s[0][1][r] + c[p][1] * s[1][1][r]
                       + c[p][2] * s[2][1][r] + c[p][3] * s[3][1][r];
            }
#pragma unroll
            for (int r = 0; r < 4; r++) {
                float mx = fmaxf(ms0[r], ms1[r]);
#pragma unroll
                for (int off = 1; off < 16; off <<= 1) mx = fmaxf(mx, __shfl_xor(mx, off));
                float mnew = fmaxf(mrow[p][r], mx);
                float alpha = __expf(mrow[p][r] - mnew);
                mrow[p][r] = mnew;
                ms0[r] = __expf(ms0[r] - mnew);
                ms1[r] = __expf(ms1[r] - mnew);
                lrow[p][r] *= alpha;
#pragma unroll
                for (int nt = 0; nt < 8; nt++) o[p][nt][r] *= alpha;
            }

            // P: D-layout -> LDS -> A-layout (wave-private; reused across p,
            // in-order LDS pipeline makes the WAR safe without a barrier)
#pragma unroll
            for (int r = 0; r < 4; r++) {
                Pb[wave][quad * 4 + r][l16]      = (bf16)ms0[r];
                Pb[wave][quad * 4 + r][16 + l16] = (bf16)ms1[r];
            }
            bf16x8 pf = *(const bf16x8*)&Pb[wave][l16][quad * 8];

            // row sums via ones-MFMA
            floatx4 s9 = __builtin_amdgcn_mfma_f32_16x16x32_bf16(
                pf, vones, (floatx4){0.f, 0.f, 0.f, 0.f}, 0, 0, 0);
#pragma unroll
            for (int r = 0; r < 4; r++) lrow[p][r] += s9[r];

            // O_p += P_p @ V_p  (Vt rows p*128 .. p*128+127, swizzled read)
#pragma unroll
            for (int nt = 0; nt < 8; nt++) {
                int r = p * 128 + nt * 16 + l16;
                bf16x8 vf = *(const bf16x8*)&Vt[r * 32 + 8 * (quad ^ (((r >> 1) ^ (r >> 2)) & 3))];
                o[p][nt] = __builtin_amdgcn_mfma_f32_16x16x32_bf16(pf, vf, o[p][nt], 0, 0, 0);
            }
        }
    }

    // epilogue: unnormalized O + (m,l) for both heads
    bf16* pod = po + (size_t)split * BN_ * C_;
#pragma unroll
    for (int p = 0; p < 2; p++) {
        int head = 2 * hg + p;
#pragma unroll
        for (int r = 0; r < 4; r++) {
            int row = n0 + wave * 16 + quad * 4 + r;
            bf16* dst = pod + (size_t)(b * N_ + row) * C_ + head * HD_;
#pragma unroll
            for (int nt = 0; nt < 8; nt++)
                dst[nt * 16 + l16] = (bf16)o[p][nt][r];
            if (l16 == 0) {
                size_t idx = ((size_t)split * BN_ + b * N_ + row) * H_ + head;
                ml[idx * 2]     = mrow[p][r];
                ml[idx * 2 + 1] = lrow[p][r];
            }
        }
    }
}

// ---------------------------------------------------------------------------
// Merge the two splits: out = (e0*O0 + e1*O1) / (e0*l0 + e1*l1)
// ---------------------------------------------------------------------------
__global__ __launch_bounds__(256) void merge_splits(const bf16* __restrict__ po,
                                                    const float* __restrict__ ml,
                                                    bf16* __restrict__ attn) {
    int id = blockIdx.x * 256 + threadIdx.x;     // 524288 threads
    int rh = id >> 4;                            // (b*N+row)*H + head
    int d0 = (id & 15) * 8;
    int row = rh >> 2, h = rh & 3;

    float m0v = ml[(size_t)rh * 2],              l0 = ml[(size_t)rh * 2 + 1];
    float m1v = ml[(size_t)(BN_ * H_ + rh) * 2], l1 = ml[(size_t)(BN_ * H_ + rh) * 2 + 1];
    float ms = fmaxf(m0v, m1v);
    float e0 = __expf(m0v - ms), e1 = __expf(m1v - ms);
    float inv = 1.0f / (e0 * l0 + e1 * l1);
    float w0 = e0 * inv, w1 = e1 * inv;

    size_t off = (size_t)row * C_ + h * HD_ + d0;
    bf16x8 a = *(const bf16x8*)(po + off);
    bf16x8 bq = *(const bf16x8*)(po + (size_t)BN_ * C_ + off);
    bf16x8 ov;
#pragma unroll
    for (int j = 0; j < 8; j++)
        ov[j] = (bf16)((float)a[j] * w0 + (float)bq[j] * w1);
    *(bf16x8*)(attn + off) = ov;
}

// ---------------------------------------------------------------------------
extern "C" void kernel_launch(void* const* d_in, const int* in_sizes, int n_in,
                              void* d_out, int out_size, void* d_ws, size_t ws_size,
                              hipStream_t stream) {
    const float* x      = (const float*)d_in[0];
    const float* w_qkv  = (const float*)d_in[1];
    const float* w_proj = (const float*)d_in[2];
    const float* b_proj = (const float*)d_in[3];
    const float* w_main = (const float*)d_in[4];
    const float* w_rest = (const float*)d_in[5];
    float* out = (float*)d_out;

    bf16* qkv = (bf16*)d_ws;                           // [8192,1536]
    bf16* xb  = qkv + (size_t)BN_ * QKVC_;             // [8192,512]
    bf16* wqb = xb + (size_t)BN_ * C_;                 // [1536,512]
    bf16* wpb = wqb + 3 * C_ * C_;                     // [512,512]
    bf16* po  = wpb + C_ * C_;                         // 2 x [8192,512]
    float* ml = (float*)(po + (size_t)2 * BN_ * C_);   // 2 x [32768][2]
    bf16* attn = xb;  // xb dead after qkv_gemm

    cvt_bf16<<<2560, 256, 0, stream>>>(x, xb, w_qkv, wqb, w_proj, wpb);
    gemm_bt<128, QKVC_, false><<<dim3(64, 12), 256, 0, stream>>>(xb, wqb, nullptr, qkv);
    flash_attn<<<512, 256, 0, stream>>>(qkv, w_main, w_rest, po, ml);
    merge_splits<<<2048, 256, 0, stream>>>(po, ml, attn);
    gemm_bt<64, C_, true><<<dim3(64, 8), 256, 0, stream>>>(attn, wpb, b_proj, out);
}

// Round 10
// 197.045 us; speedup vs baseline: 1.4891x; 1.4891x over previous
//
#include <hip/hip_runtime.h>
#include <hip/hip_bf16.h>

#define B_    8
#define N_    1024
#define C_    512
#define H_    4
#define HD_   128
#define BN_   (B_ * N_)      // 8192
#define QKVC_ 1536
#define SCALE_ 0.08838834764831845f  // 128^-0.5

typedef __bf16 bf16;
typedef __bf16 bf16x8 __attribute__((ext_vector_type(8)));
typedef float  floatx4 __attribute__((ext_vector_type(4)));

__device__ __forceinline__ void gload_lds16(const bf16* g, bf16* l) {
    __builtin_amdgcn_global_load_lds(
        (const __attribute__((address_space(1))) void*)g,
        (__attribute__((address_space(3))) void*)l, 16, 0, 0);
}

// ---------------------------------------------------------------------------
// Kernel 0: fp32 -> bf16 conversion for x, w_qkv, w_proj.
// ---------------------------------------------------------------------------
__global__ __launch_bounds__(256) void cvt_bf16(const float* __restrict__ x,  bf16* __restrict__ xb,
                                                const float* __restrict__ wq, bf16* __restrict__ wqb,
                                                const float* __restrict__ wp, bf16* __restrict__ wpb) {
    int id = blockIdx.x * 256 + threadIdx.x;
    const float* s; bf16* d; int off;
    if (id < 524288)      { s = x;  d = xb;  off = id; }
    else if (id < 622592) { s = wq; d = wqb; off = id - 524288; }
    else                  { s = wp; d = wpb; off = id - 622592; }
    const float4* sp = (const float4*)s + (size_t)off * 2;
    float4 f0 = sp[0], f1 = sp[1];
    bf16x8 v;
    v[0] = (bf16)f0.x; v[1] = (bf16)f0.y; v[2] = (bf16)f0.z; v[3] = (bf16)f0.w;
    v[4] = (bf16)f1.x; v[5] = (bf16)f1.y; v[6] = (bf16)f1.z; v[7] = (bf16)f1.w;
    ((bf16x8*)d)[off] = v;
}

// ---------------------------------------------------------------------------
// m97-class GEMM (proven): C[m][n] = sum_k A[m][k]*Bw[n][k] (+bias)
// ---------------------------------------------------------------------------
template<int TN, int NOUT, bool F32OUT>
__global__ __launch_bounds__(256) void gemm_bt(const bf16* __restrict__ A,
                                               const bf16* __restrict__ Bw,
                                               const float* __restrict__ bias,
                                               void* __restrict__ Cout) {
    constexpr int NT = TN / 32;
    const int t = threadIdx.x;
    const int wave = t >> 6, lane = t & 63;
    const int quad = lane >> 4, l16 = lane & 15;
    const int ro = lane >> 3;
    const int ch = (lane & 7) ^ ro;

    const int m_base = blockIdx.x * 128;
    const int n_base = blockIdx.y * TN;
    const int wave_r = (wave & 1) * 64;
    const int wave_c = (wave >> 1) * (TN / 2);

    __shared__ bf16 As[128 * 64];
    __shared__ bf16 Bs[TN * 64];

    floatx4 acc[4][NT] = {};

    for (int k0 = 0; k0 < 512; k0 += 64) {
        __syncthreads();
#pragma unroll
        for (int j = 0; j < 4; j++) {
            int r0 = (wave * 4 + j) * 8;
            gload_lds16(A + (size_t)(m_base + r0 + ro) * 512 + k0 + ch * 8,
                        As + r0 * 64);
        }
#pragma unroll
        for (int j = 0; j < TN / 32; j++) {
            int r0 = (wave * (TN / 32) + j) * 8;
            gload_lds16(Bw + (size_t)(n_base + r0 + ro) * 512 + k0 + ch * 8,
                        Bs + r0 * 64);
        }
        __syncthreads();

#pragma unroll
        for (int kk = 0; kk < 2; kk++) {
            const int kc = kk * 4 + quad;
            bf16x8 af[4], bfr[NT];
#pragma unroll
            for (int mt = 0; mt < 4; mt++) {
                int r = wave_r + mt * 16 + l16;
                af[mt] = *(const bf16x8*)&As[r * 64 + ((kc ^ (r & 7)) * 8)];
            }
#pragma unroll
            for (int nt = 0; nt < NT; nt++) {
                int r = wave_c + nt * 16 + l16;
                bfr[nt] = *(const bf16x8*)&Bs[r * 64 + ((kc ^ (r & 7)) * 8)];
            }
#pragma unroll
            for (int mt = 0; mt < 4; mt++)
#pragma unroll
                for (int nt = 0; nt < NT; nt++)
                    acc[mt][nt] = __builtin_amdgcn_mfma_f32_16x16x32_bf16(
                        af[mt], bfr[nt], acc[mt][nt], 0, 0, 0);
        }
    }

#pragma unroll
    for (int nt = 0; nt < NT; nt++) {
        int col = n_base + wave_c + nt * 16 + l16;
        float bi = 0.f;
        if constexpr (F32OUT) bi = bias[col];
#pragma unroll
        for (int mt = 0; mt < 4; mt++) {
#pragma unroll
            for (int r = 0; r < 4; r++) {
                int row = m_base + wave_r + mt * 16 + quad * 4 + r;
                if constexpr (F32OUT)
                    ((float*)Cout)[(size_t)row * NOUT + col] = acc[mt][nt][r] + bi;
                else
                    ((bf16*)Cout)[(size_t)row * NOUT + col] = (bf16)acc[mt][nt][r];
            }
        }
    }
}

// ---------------------------------------------------------------------------
// Fused CIM flash attention — shared-score, 2 output heads / block.
// R10: R8 structure (launch_bounds(256,2) -> no spills) + 53 KB LDS
// (3 blocks/CU resource-fit) + XCD swizzle (lin%16 = (b,split)).
// ---------------------------------------------------------------------------
__global__ __launch_bounds__(256, 2) void flash_attn(const bf16* __restrict__ qkv,
                                                     const float* __restrict__ w_main,
                                                     const float* __restrict__ w_rest,
                                                     bf16* __restrict__ po,
                                                     float* __restrict__ ml) {
    const int lin = blockIdx.x;          // 0..511
    const int bs = lin & 15;             // same-KV blocks share lin%8 -> same XCD
    const int b = bs >> 1, split = bs & 1;
    const int rest = lin >> 4;           // 0..31
    const int n0 = (rest & 15) * 64;
    const int hg = rest >> 4;            // heads 2hg, 2hg+1

    const int t = threadIdx.x;
    const int wave = t >> 6, lane = t & 63;
    const int quad = lane >> 4, l16 = lane & 15;

    // mix coefficients c[p][j] = M[2hg+p][j] * SCALE
    float c[2][4];
#pragma unroll
    for (int p = 0; p < 2; p++) {
        int i = 2 * hg + p;
#pragma unroll
        for (int j = 0; j < 4; j++) {
            float mij = (j == i) ? w_main[i]
                                 : w_rest[i * (H_ - 1) + (j - (j > i ? 1 : 0))];
            c[p][j] = mij * SCALE_;
        }
    }

    __shared__ bf16 Kt[32 * 512];        // 32 KB, XOR-swizzled
    __shared__ bf16 Vt[256 * 32];        // 16 KB, chunk-swizzled, unpadded
    __shared__ bf16 Pb[4][16][40];       // 5.1 KB, shared across p (53.1 KB tot)

    // raw Q fragments (A-layout) — mix applied to fp32 scores
    bf16x8 qf[16];
    const int qrow = n0 + wave * 16 + l16;
    const bf16* qbase = qkv + (size_t)(b * N_ + qrow) * QKVC_;
#pragma unroll
    for (int kk = 0; kk < 16; kk++)
        qf[kk] = *(const bf16x8*)(qbase + kk * 32 + quad * 8);

    bf16x8 vones;
#pragma unroll
    for (int j = 0; j < 8; j++) vones[j] = (bf16)1.0f;

    floatx4 o[2][8] = {};
    float mrow[2][4], lrow[2][4];
#pragma unroll
    for (int p = 0; p < 2; p++)
#pragma unroll
        for (int r = 0; r < 4; r++) { mrow[p][r] = -1e30f; lrow[p][r] = 0.f; }

    const bf16* kvbase = qkv + (size_t)(b * N_) * QKVC_;
    const int vg = t & 3, vp = t >> 2;   // V-stage: keys 8vg..+7, dims 4vp..+3
    const int m_begin = split * 512;

    for (int m0 = m_begin; m0 < m_begin + 512; m0 += 32) {
        __syncthreads();
        // K tile via DMA: wave w stages rows 8w..8w+7 (XOR chunk swizzle)
#pragma unroll
        for (int j = 0; j < 8; j++) {
            int r = wave * 8 + j;
            gload_lds16(kvbase + (size_t)(m0 + r) * QKVC_ + 512 + ((lane ^ (r & 7)) << 3),
                        Kt + r * 512);
        }
        // V tile (head-pair, 256 dims): register transpose, 8B loads,
        // swizzled store: chunk vg of dim-row r at vg ^ (((r>>1)^(r>>2))&3)
        {
            const bf16* vs = kvbase + (size_t)(m0 + 8 * vg) * QKVC_ + 1024 + hg * 256 + 4 * vp;
            uint2 dv[8];
#pragma unroll
            for (int j = 0; j < 8; j++)
                dv[j] = *(const uint2*)(vs + (size_t)j * QKVC_);
            uint4 rr[4];
            rr[0].x = (dv[0].x & 0xffffu) | (dv[1].x << 16);
            rr[0].y = (dv[2].x & 0xffffu) | (dv[3].x << 16);
            rr[0].z = (dv[4].x & 0xffffu) | (dv[5].x << 16);
            rr[0].w = (dv[6].x & 0xffffu) | (dv[7].x << 16);
            rr[1].x = (dv[0].x >> 16) | (dv[1].x & 0xffff0000u);
            rr[1].y = (dv[2].x >> 16) | (dv[3].x & 0xffff0000u);
            rr[1].z = (dv[4].x >> 16) | (dv[5].x & 0xffff0000u);
            rr[1].w = (dv[6].x >> 16) | (dv[7].x & 0xffff0000u);
            rr[2].x = (dv[0].y & 0xffffu) | (dv[1].y << 16);
            rr[2].y = (dv[2].y & 0xffffu) | (dv[3].y << 16);
            rr[2].z = (dv[4].y & 0xffffu) | (dv[5].y << 16);
            rr[2].w = (dv[6].y & 0xffffu) | (dv[7].y << 16);
            rr[3].x = (dv[0].y >> 16) | (dv[1].y & 0xffff0000u);
            rr[3].y = (dv[2].y >> 16) | (dv[3].y & 0xffff0000u);
            rr[3].z = (dv[4].y >> 16) | (dv[5].y & 0xffff0000u);
            rr[3].w = (dv[6].y >> 16) | (dv[7].y & 0xffff0000u);
#pragma unroll
            for (int i = 0; i < 4; i++) {
                int r = 4 * vp + i;
                *(uint4*)&Vt[r * 32 + 8 * (vg ^ (((r >> 1) ^ (r >> 2)) & 3))] = rr[i];
            }
        }
        __syncthreads();

        // Per-head scores: s[j] = q_j @ k_j^T  (one pass over 512 cols)
        floatx4 s[4][2] = {};
#pragma unroll
        for (int kk = 0; kk < 16; kk++) {
#pragma unroll
            for (int nt = 0; nt < 2; nt++) {
                int r = nt * 16 + l16;
                bf16x8 kb = *(const bf16x8*)&Kt[r * 512 + (((kk * 4 + quad) ^ (r & 7)) << 3)];
                s[kk >> 2][nt] = __builtin_amdgcn_mfma_f32_16x16x32_bf16(
                    qf[kk], kb, s[kk >> 2][nt], 0, 0, 0);
            }
        }

        // Per output head p: mix -> online softmax -> P staging -> PV
#pragma unroll
        for (int p = 0; p < 2; p++) {
            floatx4 ms0, ms1;
#pragma unroll
            for (int r = 0; r < 4; r++) {
                ms0[r] = c[p][0] * s[0][0][r] + c[p][1] * s[1][0][r]
                       + c[p][2] * s[2][0][r] + c[p][3] * s[3][0][r];
                ms1[r] = c[p][0] * s[0][1][r] + c[p][1] * s[1][1][r]
                       + c[p][2] * s[2][1][r] + c[p][3] * s[3][1][r];
            }
#pragma unroll
            for (int r = 0; r < 4; r++) {
                float mx = fmaxf(ms0[r], ms1[r]);
#pragma unroll
                for (int off = 1; off < 16; off <<= 1) mx = fmaxf(mx, __shfl_xor(mx, off));
                float mnew = fmaxf(mrow[p][r], mx);
                float alpha = __expf(mrow[p][r] - mnew);
                mrow[p][r] = mnew;
                ms0[r] = __expf(ms0[r] - mnew);
                ms1[r] = __expf(ms1[r] - mnew);
                lrow[p][r] *= alpha;
#pragma unroll
                for (int nt = 0; nt < 8; nt++) o[p][nt][r] *= alpha;
            }

            // P: D-layout -> LDS -> A-layout (wave-private; reused across p —
            // same-wave LDS ops are in-order so the WAR needs no barrier)
#pragma unroll
            for (int r = 0; r < 4; r++) {
                Pb[wave][quad * 4 + r][l16]      = (bf16)ms0[r];
                Pb[wave][quad * 4 + r][16 + l16] = (bf16)ms1[r];
            }
            bf16x8 pf = *(const bf16x8*)&Pb[wave][l16][quad * 8];

            // row sums via ones-MFMA
            floatx4 s9 = __builtin_amdgcn_mfma_f32_16x16x32_bf16(
                pf, vones, (floatx4){0.f, 0.f, 0.f, 0.f}, 0, 0, 0);
#pragma unroll
            for (int r = 0; r < 4; r++) lrow[p][r] += s9[r];

            // O_p += P_p @ V_p  (Vt rows p*128 .. p*128+127, swizzled read)
#pragma unroll
            for (int nt = 0; nt < 8; nt++) {
                int r = p * 128 + nt * 16 + l16;
                bf16x8 vf = *(const bf16x8*)&Vt[r * 32 + 8 * (quad ^ (((r >> 1) ^ (r >> 2)) & 3))];
                o[p][nt] = __builtin_amdgcn_mfma_f32_16x16x32_bf16(pf, vf, o[p][nt], 0, 0, 0);
            }
        }
    }

    // epilogue: unnormalized O + (m,l) for both heads
    bf16* pod = po + (size_t)split * BN_ * C_;
#pragma unroll
    for (int p = 0; p < 2; p++) {
        int head = 2 * hg + p;
#pragma unroll
        for (int r = 0; r < 4; r++) {
            int row = n0 + wave * 16 + quad * 4 + r;
            bf16* dst = pod + (size_t)(b * N_ + row) * C_ + head * HD_;
#pragma unroll
            for (int nt = 0; nt < 8; nt++)
                dst[nt * 16 + l16] = (bf16)o[p][nt][r];
            if (l16 == 0) {
                size_t idx = ((size_t)split * BN_ + b * N_ + row) * H_ + head;
                ml[idx * 2]     = mrow[p][r];
                ml[idx * 2 + 1] = lrow[p][r];
            }
        }
    }
}

// ---------------------------------------------------------------------------
// Merge the two splits: out = (e0*O0 + e1*O1) / (e0*l0 + e1*l1)
// ---------------------------------------------------------------------------
__global__ __launch_bounds__(256) void merge_splits(const bf16* __restrict__ po,
                                                    const float* __restrict__ ml,
                                                    bf16* __restrict__ attn) {
    int id = blockIdx.x * 256 + threadIdx.x;     // 524288 threads
    int rh = id >> 4;                            // (b*N+row)*H + head
    int d0 = (id & 15) * 8;
    int row = rh >> 2, h = rh & 3;

    float m0v = ml[(size_t)rh * 2],              l0 = ml[(size_t)rh * 2 + 1];
    float m1v = ml[(size_t)(BN_ * H_ + rh) * 2], l1 = ml[(size_t)(BN_ * H_ + rh) * 2 + 1];
    float ms = fmaxf(m0v, m1v);
    float e0 = __expf(m0v - ms), e1 = __expf(m1v - ms);
    float inv = 1.0f / (e0 * l0 + e1 * l1);
    float w0 = e0 * inv, w1 = e1 * inv;

    size_t off = (size_t)row * C_ + h * HD_ + d0;
    bf16x8 a = *(const bf16x8*)(po + off);
    bf16x8 bq = *(const bf16x8*)(po + (size_t)BN_ * C_ + off);
    bf16x8 ov;
#pragma unroll
    for (int j = 0; j < 8; j++)
        ov[j] = (bf16)((float)a[j] * w0 + (float)bq[j] * w1);
    *(bf16x8*)(attn + off) = ov;
}

// ---------------------------------------------------------------------------
extern "C" void kernel_launch(void* const* d_in, const int* in_sizes, int n_in,
                              void* d_out, int out_size, void* d_ws, size_t ws_size,
                              hipStream_t stream) {
    const float* x      = (const float*)d_in[0];
    const float* w_qkv  = (const float*)d_in[1];
    const float* w_proj = (const float*)d_in[2];
    const float* b_proj = (const float*)d_in[3];
    const float* w_main = (const float*)d_in[4];
    const float* w_rest = (const float*)d_in[5];
    float* out = (float*)d_out;

    bf16* qkv = (bf16*)d_ws;                           // [8192,1536]
    bf16* xb  = qkv + (size_t)BN_ * QKVC_;             // [8192,512]
    bf16* wqb = xb + (size_t)BN_ * C_;                 // [1536,512]
    bf16* wpb = wqb + 3 * C_ * C_;                     // [512,512]
    bf16* po  = wpb + C_ * C_;                         // 2 x [8192,512]
    float* ml = (float*)(po + (size_t)2 * BN_ * C_);   // 2 x [32768][2]
    bf16* attn = xb;  // xb dead after qkv_gemm

    cvt_bf16<<<2560, 256, 0, stream>>>(x, xb, w_qkv, wqb, w_proj, wpb);
    gemm_bt<128, QKVC_, false><<<dim3(64, 12), 256, 0, stream>>>(xb, wqb, nullptr, qkv);
    flash_attn<<<512, 256, 0, stream>>>(qkv, w_main, w_rest, po, ml);
    merge_splits<<<2048, 256, 0, stream>>>(po, ml, attn);
    gemm_bt<64, C_, true><<<dim3(64, 8), 256, 0, stream>>>(attn, wpb, b_proj, out);
}